// Round 2
// baseline (379.127 us; speedup 1.0000x reference)
//
#include <hip/hip_runtime.h>
#include <stdint.h>
#include <stddef.h>

// Problem constants (B, F, D) = (1024, 16, 64); P = 120
constexpr int NB = 1024;
constexpr int NF = 16;
constexpr int ND = 64;
constexpr int NP = 120;
constexpr int KD = ND * ND;          // 4096 contraction length per pair
constexpr int OUT_STRIDE = NP * ND;  // 7680 floats per batch row

using floatx4 = __attribute__((ext_vector_type(4))) float;
using short8  = __attribute__((ext_vector_type(8))) short;
using uint4v  = __attribute__((ext_vector_type(4))) uint32_t;
using ushort4v = __attribute__((ext_vector_type(4))) uint16_t;

constexpr int XT_STRIDE = 264;  // bf16 elems/row of xi^T: 256 cols + 8 pad (528 B rows, 16B-aligned)
constexpr int BT_STRIDE = 72;   // bf16 elems/row of W tile: 144 B rows (16B-aligned)

// round-half-up f32->bf16 pair packed into one dword (2 add + 1 perm)
__device__ __forceinline__ uint32_t pack_bf16(float f0, float f1) {
    uint32_t u0 = __float_as_uint(f0) + 0x8000u;
    uint32_t u1 = __float_as_uint(f1) + 0x8000u;
    return __builtin_amdgcn_perm(u1, u0, 0x07060302u);  // (hi16(u1)<<16)|hi16(u0)
}

__device__ __forceinline__ uint16_t to_bf16(float f) {
    return (uint16_t)((__float_as_uint(f) + 0x8000u) >> 16);
}

__device__ __forceinline__ float from_bf16(uint16_t u) {
    return __uint_as_float(((uint32_t)u) << 16);
}

__global__ __launch_bounds__(256, 2)
void outer_kernel(const float* __restrict__ x, const float* __restrict__ W,
                  const float* __restrict__ bias, float* __restrict__ out)
{
    __shared__ uint16_t lds_xit[ND * XT_STRIDE];     // xi^T, bf16: 33,792 B
    __shared__ uint16_t lds_bt[2][ND * BT_STRIDE];   // W a-tile double buffer: 18,432 B
    // total 52,224 B -> 2 blocks/CU

    const int p  = blockIdx.x;        // pair 0..119
    const int b0 = blockIdx.y * 256;  // batch tile origin

    // triu_indices(16, k=1) order
    int icol = 0, rem = p;
    while (rem >= NF - 1 - icol) { rem -= NF - 1 - icol; ++icol; }
    const int jcol = icol + 1 + rem;

    const int t    = threadIdx.x;
    const int wave = t >> 6;
    const int lane = t & 63;
    const int r    = lane & 15;
    const int quad = lane >> 4;

    // ---- stage xi transposed: lds_xit[a][m] = bf16(x[b0+m][icol][a]) ----
    {
        const float* src = x + (size_t)(b0 + t) * (NF * ND) + icol * ND;
        #pragma unroll
        for (int c = 0; c < ND; c += 4) {
            floatx4 v = *(const floatx4*)(src + c);
            lds_xit[(c + 0) * XT_STRIDE + t] = to_bf16(v.x);
            lds_xit[(c + 1) * XT_STRIDE + t] = to_bf16(v.y);
            lds_xit[(c + 2) * XT_STRIDE + t] = to_bf16(v.z);
            lds_xit[(c + 3) * XT_STRIDE + t] = to_bf16(v.w);
        }
    }

    // ---- loop-invariant A-fragments: af[ms][ks] = bf16(xj) in MFMA A layout ----
    // 16x16x32 A: lane holds A[m = lane&15][k = quad*8 + j]
    short8 afrag[4][2];
    #pragma unroll
    for (int ms = 0; ms < 4; ++ms) {
        const float* srow = x + (size_t)(b0 + wave*64 + ms*16 + r) * (NF * ND)
                              + jcol * ND + quad * 8;
        #pragma unroll
        for (int ks = 0; ks < 2; ++ks) {
            floatx4 v0 = *(const floatx4*)(srow + ks * 32);
            floatx4 v1 = *(const floatx4*)(srow + ks * 32 + 4);
            union { short8 s; uint32_t u[4]; } af;
            af.u[0] = pack_bf16(v0.x, v0.y);
            af.u[1] = pack_bf16(v0.z, v0.w);
            af.u[2] = pack_bf16(v1.x, v1.y);
            af.u[3] = pack_bf16(v1.z, v1.w);
            afrag[ms][ks] = af.s;
        }
    }

    // ---- W staging: thread covers (n_st, c_st..c_st+15) of the 64x64 a-tile ----
    const int n_st = t >> 2;
    const int c_st = (t & 3) * 16;
    const float* wsrc = W + ((size_t)p * ND + n_st) * KD + c_st;
    uint16_t* bdst0 = &lds_bt[0][n_st * BT_STRIDE + c_st];
    uint16_t* bdst1 = &lds_bt[1][n_st * BT_STRIDE + c_st];

    floatx4 wreg[2][4];

    // stage a=0 into buf0; prefetch a=1 into wreg[1]
    #pragma unroll
    for (int q = 0; q < 4; ++q) wreg[0][q] = *(const floatx4*)(wsrc + q * 4);
    {
        uint4v q0 = (uint4v){ pack_bf16(wreg[0][0].x, wreg[0][0].y), pack_bf16(wreg[0][0].z, wreg[0][0].w),
                              pack_bf16(wreg[0][1].x, wreg[0][1].y), pack_bf16(wreg[0][1].z, wreg[0][1].w) };
        uint4v q1 = (uint4v){ pack_bf16(wreg[0][2].x, wreg[0][2].y), pack_bf16(wreg[0][2].z, wreg[0][2].w),
                              pack_bf16(wreg[0][3].x, wreg[0][3].y), pack_bf16(wreg[0][3].z, wreg[0][3].w) };
        *(uint4v*)(bdst0)     = q0;
        *(uint4v*)(bdst0 + 8) = q1;
    }
    #pragma unroll
    for (int q = 0; q < 4; ++q) wreg[1][q] = *(const floatx4*)(wsrc + ND + q * 4);
    __syncthreads();

    floatx4 acc[4][4] = {};              // output accumulators (fp32)
    const floatx4 zerof = (floatx4){0.f, 0.f, 0.f, 0.f};

    #pragma unroll 2
    for (int a = 0; a < ND; ++a) {
        const int cur = a & 1;

        // (1) issue global prefetch of W(a+2) into wreg[cur] (full-iteration flight window)
        if (a + 2 < ND) {
            const float* wn = wsrc + (size_t)(a + 2) * ND;
            #pragma unroll
            for (int q = 0; q < 4; ++q) wreg[cur][q] = *(const floatx4*)(wn + q * 4);
        }

        // (2) B-fragments from current buffer: lane holds B[k=quad*8+j][n=r]
        short8 bf[4][2];
        #pragma unroll
        for (int ns = 0; ns < 4; ++ns)
            #pragma unroll
            for (int ks = 0; ks < 2; ++ks)
                bf[ns][ks] = *(const short8*)&lds_bt[cur][(ns*16 + r) * BT_STRIDE
                                                          + ks*32 + quad*8];

        // xi values for this a: rows ms*16 + quad*4 + reg (matches C-frag rows)
        float xiv[4][4];
        #pragma unroll
        for (int ms = 0; ms < 4; ++ms) {
            ushort4v xv = *(const ushort4v*)&lds_xit[a * XT_STRIDE
                                                     + wave*64 + ms*16 + quad*4];
            xiv[ms][0] = from_bf16(xv.x);
            xiv[ms][1] = from_bf16(xv.y);
            xiv[ms][2] = from_bf16(xv.z);
            xiv[ms][3] = from_bf16(xv.w);
        }

        // (3) S_a = xj @ W_a^T per subtile, then acc += xi[:,a] * S_a
        #pragma unroll
        for (int ms = 0; ms < 4; ++ms) {
            #pragma unroll
            for (int ns = 0; ns < 4; ++ns) {
                floatx4 tacc = __builtin_amdgcn_mfma_f32_16x16x32_bf16(
                    afrag[ms][0], bf[ns][0], zerof, 0, 0, 0);
                tacc = __builtin_amdgcn_mfma_f32_16x16x32_bf16(
                    afrag[ms][1], bf[ns][1], tacc, 0, 0, 0);
                #pragma unroll
                for (int reg = 0; reg < 4; ++reg)
                    acc[ms][ns][reg] += xiv[ms][reg] * tacc[reg];
            }
        }

        // (4) pack W(a+1) (loaded last iter) into the other buffer
        if (a + 1 < ND) {
            const floatx4* wr = wreg[1 - cur];
            uint4v q0 = (uint4v){ pack_bf16(wr[0].x, wr[0].y), pack_bf16(wr[0].z, wr[0].w),
                                  pack_bf16(wr[1].x, wr[1].y), pack_bf16(wr[1].z, wr[1].w) };
            uint4v q1 = (uint4v){ pack_bf16(wr[2].x, wr[2].y), pack_bf16(wr[2].z, wr[2].w),
                                  pack_bf16(wr[3].x, wr[3].y), pack_bf16(wr[3].z, wr[3].w) };
            uint16_t* bd = (cur ? bdst0 : bdst1);
            *(uint4v*)(bd)     = q0;
            *(uint4v*)(bd + 8) = q1;
        }

        // (5) single barrier per a-step
        __syncthreads();
    }

    // ---- epilogue: bias + store. C/D: col = lane&15, row = quad*4 + reg ----
    #pragma unroll
    for (int ns = 0; ns < 4; ++ns) {
        const float bb = bias[p * ND + ns*16 + r];
        #pragma unroll
        for (int ms = 0; ms < 4; ++ms) {
            #pragma unroll
            for (int reg = 0; reg < 4; ++reg) {
                const int row = b0 + wave*64 + ms*16 + quad*4 + reg;
                out[(size_t)row * OUT_STRIDE + p * ND + ns*16 + r]
                    = acc[ms][ns][reg] + bb;
            }
        }
    }
}

extern "C" void kernel_launch(void* const* d_in, const int* in_sizes, int n_in,
                              void* d_out, int out_size, void* d_ws, size_t ws_size,
                              hipStream_t stream) {
    const float* x    = (const float*)d_in[0];  // (1024, 16, 64)
    const float* W    = (const float*)d_in[1];  // (120, 64, 4096)
    const float* bias = (const float*)d_in[2];  // (120, 64)
    float* out = (float*)d_out;                 // (1024, 120, 64)

    dim3 grid(NP, NB / 256);   // 480 blocks; 120 mod 8 == 0 keeps same-p blocks on one XCD
    outer_kernel<<<grid, 256, 0, stream>>>(x, W, bias, out);
}

// Round 3
// 224.024 us; speedup vs baseline: 1.6924x; 1.6924x over previous
//
#include <hip/hip_runtime.h>
#include <stdint.h>
#include <stddef.h>

// Problem constants (B, F, D) = (1024, 16, 64); P = 120
constexpr int NB = 1024;
constexpr int NF = 16;
constexpr int ND = 64;
constexpr int NP = 120;
constexpr int KD = ND * ND;          // 4096 contraction length per pair
constexpr int OUT_STRIDE = NP * ND;  // 7680 floats per batch row

using floatx4  = __attribute__((ext_vector_type(4))) float;
using short8   = __attribute__((ext_vector_type(8))) short;
using uint4v   = __attribute__((ext_vector_type(4))) uint32_t;
using ushort4v = __attribute__((ext_vector_type(4))) uint16_t;

constexpr int XT_STRIDE = 264;  // ushorts per xi^T row: 256 m + 8 pad (528 B, 16B-aligned)
constexpr int BT_STRIDE = 72;   // ushorts per W-tile row (144 B, 16B-aligned)
constexpr int BT_BUF    = ND * BT_STRIDE;  // elems per W buffer

// round-half-up f32->bf16 pair packed into one dword: low = bf16(f0), high = bf16(f1)
__device__ __forceinline__ uint32_t pack_bf16(float f0, float f1) {
    uint32_t u0 = __float_as_uint(f0) + 0x8000u;
    uint32_t u1 = __float_as_uint(f1) + 0x8000u;
    return __builtin_amdgcn_perm(u1, u0, 0x07060302u);
}
__device__ __forceinline__ uint16_t to_bf16(float f) {
    return (uint16_t)((__float_as_uint(f) + 0x8000u) >> 16);
}
__device__ __forceinline__ float from_bf16(uint16_t u) {
    return __uint_as_float(((uint32_t)u) << 16);
}

__global__ __launch_bounds__(256, 2)
void outer_kernel(const float* __restrict__ x, const float* __restrict__ W,
                  const float* __restrict__ bias, float* __restrict__ out)
{
    __shared__ uint16_t lds_xit[ND * XT_STRIDE];  // xi^T bf16: 33,792 B
    __shared__ uint16_t lds_bt[2 * BT_BUF];       // W a-tile dbuf: 18,432 B (total 52,224)

    const int p  = blockIdx.x;        // pair 0..119
    const int b0 = blockIdx.y * 256;  // batch tile origin

    // triu_indices(16, k=1) order
    int icol = 0, rem = p;
    while (rem >= NF - 1 - icol) { rem -= NF - 1 - icol; ++icol; }
    const int jcol = icol + 1 + rem;

    const int t    = threadIdx.x;
    const int wave = t >> 6;
    const int lane = t & 63;
    const int r    = lane & 15;
    const int quad = lane >> 4;

    // ---- stage xi transposed: lds_xit[a*XT_STRIDE + m] = bf16(x[b0+m][icol][a]) ----
    {
        const float* src = x + (size_t)(b0 + t) * (NF * ND) + icol * ND;
        #pragma unroll
        for (int c = 0; c < ND; c += 4) {
            floatx4 v = *(const floatx4*)(src + c);
            lds_xit[(c + 0) * XT_STRIDE + t] = to_bf16(v.x);
            lds_xit[(c + 1) * XT_STRIDE + t] = to_bf16(v.y);
            lds_xit[(c + 2) * XT_STRIDE + t] = to_bf16(v.z);
            lds_xit[(c + 3) * XT_STRIDE + t] = to_bf16(v.w);
        }
    }

    // ---- loop-invariant A-fragments: bf16(xj) in MFMA A layout (16x16x32) ----
    // lane holds A[m = lane&15][k = quad*8 + j]
    short8 afrag[4][2];
    #pragma unroll
    for (int ms = 0; ms < 4; ++ms) {
        const float* srow = x + (size_t)(b0 + wave*64 + ms*16 + r) * (NF * ND)
                              + jcol * ND + quad * 8;
        #pragma unroll
        for (int ks = 0; ks < 2; ++ks) {
            floatx4 v0 = *(const floatx4*)(srow + ks * 32);
            floatx4 v1 = *(const floatx4*)(srow + ks * 32 + 4);
            union { short8 s; uint32_t u[4]; } af;
            af.u[0] = pack_bf16(v0.x, v0.y);
            af.u[1] = pack_bf16(v0.z, v0.w);
            af.u[2] = pack_bf16(v1.x, v1.y);
            af.u[3] = pack_bf16(v1.z, v1.w);
            afrag[ms][ks] = af.s;
        }
    }

    // ---- W staging: thread covers (n_st, c_st..c_st+15) of the 64x64 a-tile ----
    const int n_st = t >> 2;
    const int c_st = (t & 3) * 16;
    const float* wsrc = W + ((size_t)p * ND + n_st) * KD + c_st;
    uint16_t* bdst0 = &lds_bt[n_st * BT_STRIDE + c_st];

    floatx4 wreg[4];

    // prologue: stage W(0) into buf0; prefetch W(1) into wreg
    #pragma unroll
    for (int q = 0; q < 4; ++q) wreg[q] = *(const floatx4*)(wsrc + q * 4);
    {
        uint4v q0 = (uint4v){ pack_bf16(wreg[0].x, wreg[0].y), pack_bf16(wreg[0].z, wreg[0].w),
                              pack_bf16(wreg[1].x, wreg[1].y), pack_bf16(wreg[1].z, wreg[1].w) };
        uint4v q1 = (uint4v){ pack_bf16(wreg[2].x, wreg[2].y), pack_bf16(wreg[2].z, wreg[2].w),
                              pack_bf16(wreg[3].x, wreg[3].y), pack_bf16(wreg[3].z, wreg[3].w) };
        *(uint4v*)(bdst0)     = q0;
        *(uint4v*)(bdst0 + 8) = q1;
    }
    #pragma unroll
    for (int q = 0; q < 4; ++q) wreg[q] = *(const floatx4*)(wsrc + ND + q * 4);
    __syncthreads();

    floatx4 acc[4][4] = {};
    const floatx4 zerof = (floatx4){0.f, 0.f, 0.f, 0.f};

    #pragma unroll 1
    for (int a = 0; a < ND; ++a) {
        const int cur = a & 1;
        const uint16_t* rbuf = lds_bt + cur * BT_BUF;  // holds W(a)

        // xi for this a, rows matching C-frag rows (quad*4 + reg)
        float xiv[4][4];
        #pragma unroll
        for (int ms = 0; ms < 4; ++ms) {
            ushort4v xu = *(const ushort4v*)&lds_xit[a * XT_STRIDE
                                                     + wave*64 + ms*16 + quad*4];
            xiv[ms][0] = from_bf16(xu.x);
            xiv[ms][1] = from_bf16(xu.y);
            xiv[ms][2] = from_bf16(xu.z);
            xiv[ms][3] = from_bf16(xu.w);
        }

        // S_a = xj @ W_a^T per subtile; acc += xi[:,a] * S_a
        #pragma unroll
        for (int ns = 0; ns < 4; ++ns) {
            const int brow = (ns*16 + r) * BT_STRIDE + quad * 8;
            short8 bf0 = *(const short8*)&rbuf[brow];
            short8 bf1 = *(const short8*)&rbuf[brow + 32];
            #pragma unroll
            for (int ms = 0; ms < 4; ++ms) {
                floatx4 tv = __builtin_amdgcn_mfma_f32_16x16x32_bf16(
                    afrag[ms][0], bf0, zerof, 0, 0, 0);
                tv = __builtin_amdgcn_mfma_f32_16x16x32_bf16(
                    afrag[ms][1], bf1, tv, 0, 0, 0);
                #pragma unroll
                for (int reg = 0; reg < 4; ++reg)
                    acc[ms][ns][reg] = __builtin_fmaf(xiv[ms][reg], tv[reg],
                                                      acc[ms][ns][reg]);
            }
        }

        // pack W(a+1) (in wreg) into the other buffer; then prefetch W(a+2)
        if (a + 1 < ND) {
            uint16_t* bd = bdst0 + (cur ^ 1) * BT_BUF;
            uint4v q0 = (uint4v){ pack_bf16(wreg[0].x, wreg[0].y), pack_bf16(wreg[0].z, wreg[0].w),
                                  pack_bf16(wreg[1].x, wreg[1].y), pack_bf16(wreg[1].z, wreg[1].w) };
            uint4v q1 = (uint4v){ pack_bf16(wreg[2].x, wreg[2].y), pack_bf16(wreg[2].z, wreg[2].w),
                                  pack_bf16(wreg[3].x, wreg[3].y), pack_bf16(wreg[3].z, wreg[3].w) };
            *(uint4v*)(bd)     = q0;
            *(uint4v*)(bd + 8) = q1;
        }
        if (a + 2 < ND) {
            const float* wn = wsrc + (size_t)(a + 2) * ND;
            #pragma unroll
            for (int q = 0; q < 4; ++q) wreg[q] = *(const floatx4*)(wn + q * 4);
        }

        __syncthreads();  // single barrier per a-step
    }

    // ---- epilogue: bias + store. C/D: col = lane&15, row = quad*4 + reg ----
    #pragma unroll
    for (int ns = 0; ns < 4; ++ns) {
        const float bb = bias[p * ND + ns*16 + r];
        #pragma unroll
        for (int ms = 0; ms < 4; ++ms) {
            #pragma unroll
            for (int reg = 0; reg < 4; ++reg) {
                const int row = b0 + wave*64 + ms*16 + quad*4 + reg;
                out[(size_t)row * OUT_STRIDE + p * ND + ns*16 + r]
                    = acc[ms][ns][reg] + bb;
            }
        }
    }
}

extern "C" void kernel_launch(void* const* d_in, const int* in_sizes, int n_in,
                              void* d_out, int out_size, void* d_ws, size_t ws_size,
                              hipStream_t stream) {
    const float* x    = (const float*)d_in[0];  // (1024, 16, 64)
    const float* W    = (const float*)d_in[1];  // (120, 64, 4096)
    const float* bias = (const float*)d_in[2];  // (120, 64)
    float* out = (float*)d_out;                 // (1024, 120, 64)

    dim3 grid(NP, NB / 256);   // 480 blocks; same-p blocks land on one XCD (120 % 8 == 0)
    outer_kernel<<<grid, 256, 0, stream>>>(x, W, bias, out);
}